// Round 10
// baseline (1977.767 us; speedup 1.0000x reference)
//
#include <hip/hip_runtime.h>
#include <stdint.h>

#define DIM 3072
#define HEADS 24
#define HD 128
#define RANKN 64
#define CONDN 1024
#define BLK 2048
#define SEQN 3072
#define NIPN 64

typedef __attribute__((ext_vector_type(8))) short s8v;
typedef __attribute__((ext_vector_type(4))) float fx4;

static __device__ __forceinline__ unsigned short f2bf(float f){
  union{float f; unsigned u;} v; v.f=f;
  unsigned r = v.u + 0x7FFFu + ((v.u>>16)&1u);
  return (unsigned short)(r>>16);
}
static __device__ __forceinline__ float bf2f(unsigned short b){
  union{unsigned u; float f;} v; v.u = ((unsigned)b) << 16;
  return v.f;
}

#define GL16(g,l) __builtin_amdgcn_global_load_lds((const __attribute__((address_space(1))) void*)(g), (__attribute__((address_space(3))) void*)(l), 16, 0, 0)
#define MFMA(a,b,c) __builtin_amdgcn_mfma_f32_16x16x32_bf16((a),(b),(c),0,0,0)

// ---------------- fp32 -> bf16 convert (4 elems/thread) ----------------
__global__ __launch_bounds__(256) void cvt_f32_bf16(const float* __restrict__ src,
                                                    unsigned short* __restrict__ dst, int n4){
  int i = blockIdx.x*256 + threadIdx.x;
  if (i < n4){
    float4 v = ((const float4*)src)[i];
    ushort4 o;
    o.x = f2bf(v.x); o.y = f2bf(v.y); o.z = f2bf(v.z); o.w = f2bf(v.w);
    ((ushort4*)dst)[i] = o;
  }
}

// ---------------- LoRA down (MFMA): downb[z][1024][64], z=0:k 1:v ----------------
__global__ __launch_bounds__(256) void lora_down_g(const unsigned short* __restrict__ A,
                                                   const unsigned short* __restrict__ D0,
                                                   const unsigned short* __restrict__ D1,
                                                   unsigned short* __restrict__ outb){
  __shared__ unsigned short As[128*64];
  __shared__ unsigned short Bs[64*64];
  int tid = threadIdx.x, lane = tid & 63, w = tid >> 6;
  int l15 = lane & 15, l16 = lane >> 4;
  int z = blockIdx.z;
  int m0 = blockIdx.y * 128;
  const unsigned short* Dw = z ? D1 : D0;
  int wr = w * 32;
  fx4 acc[2][4] = {};
  for (int kt = 0; kt < DIM; kt += 64){
    #pragma unroll
    for (int i = 0; i < 4; i++){
      int p = i*256 + tid;
      int row = p >> 3, cc = p & 7;
      int gc = cc ^ (row & 7);
      GL16(A + (size_t)(m0+row)*DIM + kt + gc*8, As + p*8);
    }
    #pragma unroll
    for (int i = 0; i < 2; i++){
      int p = i*256 + tid;
      int row = p >> 3, cc = p & 7;
      int gc = cc ^ (row & 7);
      GL16(Dw + (size_t)row*DIM + kt + gc*8, Bs + p*8);
    }
    __syncthreads();
    #pragma unroll
    for (int kk = 0; kk < 2; kk++){
      s8v af[2], bfr[4];
      #pragma unroll
      for (int t = 0; t < 2; t++){
        int rowa = wr + t*16 + l15;
        int ca = (kk*4 + l16) ^ (rowa & 7);
        af[t] = *(const s8v*)(As + rowa*64 + ca*8);
      }
      #pragma unroll
      for (int t = 0; t < 4; t++){
        int rowb = t*16 + l15;
        int cb = (kk*4 + l16) ^ (rowb & 7);
        bfr[t] = *(const s8v*)(Bs + rowb*64 + cb*8);
      }
      #pragma unroll
      for (int mt = 0; mt < 2; mt++)
        #pragma unroll
        for (int nt = 0; nt < 4; nt++)
          acc[mt][nt] = MFMA(af[mt], bfr[nt], acc[mt][nt]);
    }
    __syncthreads();
  }
  #pragma unroll
  for (int mt = 0; mt < 2; mt++)
    #pragma unroll
    for (int j = 0; j < 4; j++){
      int row = m0 + wr + mt*16 + l16*4 + j;
      #pragma unroll
      for (int nt = 0; nt < 4; nt++){
        int col = nt*16 + l15;
        outb[((size_t)z*CONDN + row)*64 + col] = f2bf(acc[mt][nt][j]);
      }
    }
}

// ---------------- 256x256 QKV GEMM: BK=32, 64KB LDS, 2 blocks/CU ----------------
// 408 blocks x 512 threads. id: [0,96) q | [96,240) k | [240,384) v | [384,408) ip.
__global__ __launch_bounds__(512, 4) void gemm_256(
    const unsigned short* __restrict__ hs_bf,
    const unsigned short* __restrict__ ie_bf,
    const unsigned short* __restrict__ Wq,
    const unsigned short* __restrict__ Wk,
    const unsigned short* __restrict__ Wv,
    const unsigned short* __restrict__ Wik,
    const unsigned short* __restrict__ Wiv,
    const float* __restrict__ bq, const float* __restrict__ bk, const float* __restrict__ bv,
    const unsigned short* __restrict__ downb,
    const unsigned short* __restrict__ upk,
    const unsigned short* __restrict__ upv,
    unsigned short* __restrict__ qb, unsigned short* __restrict__ kb, unsigned short* __restrict__ vb,
    float* __restrict__ ipk_pre, float* __restrict__ ipv_pre)
{
  __shared__ unsigned short S[32768];   // 64 KB: A buf0/buf1 at 0/8192, B at 16384/24576 (ushorts)
  int tid = threadIdx.x, lane = tid & 63, w = tid >> 6;
  int wm = w >> 2, wn = w & 3;
  int l15 = lane & 15, l16 = lane >> 4;

  int b = blockIdx.x;
  int id = (b & 7) * 51 + (b >> 3);        // bijective XCD-chunked swizzle (408 = 8*51)
  int z, mt, ntile;
  if (id < 96){ z = 0; mt = id / 12; ntile = id % 12; }
  else if (id < 240){ z = 1; int r = id - 96; mt = r / 12; ntile = r % 12; }
  else if (id < 384){ z = 2; int r = id - 240; mt = r / 12; ntile = r % 12; }
  else { z = 3; int r = id - 384; mt = r / 12; ntile = r % 12; }
  const bool is_ip = (z == 3);
  int z2 = is_ip ? mt : 0;
  int m0 = is_ip ? 0 : mt * 256;
  int n0 = ntile * 256;
  const unsigned short* A = is_ip ? ie_bf : hs_bf;
  const unsigned short* B = is_ip ? (z2 ? Wiv : Wik)
                                  : (z == 0 ? Wq : (z == 1 ? Wk : Wv));

  fx4 acc[8][4] = {};
  s8v af[8], bfr[4];

  // stage one 256x32 tile (16 KB): p in [0,1024), row=p>>2, chunk cc=p&3
  auto stA = [&](int buf, int kt){
    #pragma unroll
    for (int i = 0; i < 2; i++){
      int p = i*512 + tid;
      int row = p >> 2, cc = p & 3, gc = cc ^ (row & 3);
      int ar = m0 + row;
      if (is_ip && ar > 63) ar = 63;
      GL16(A + (size_t)ar*DIM + kt + gc*8, S + buf*8192 + p*8);
    }
  };
  auto stB = [&](int buf, int kt){
    #pragma unroll
    for (int i = 0; i < 2; i++){
      int p = i*512 + tid;
      int row = p >> 2, cc = p & 3, gc = cc ^ (row & 3);
      GL16(B + (size_t)(n0 + row)*DIM + kt + gc*8, S + 16384 + buf*8192 + p*8);
    }
  };
  auto rdA = [&](int buf, int m)->s8v{
    int rl = wm*128 + m*16 + l15;
    return *(const s8v*)(S + buf*8192 + rl*32 + ((l16 ^ (rl & 3))*8));
  };
  auto rdB = [&](int buf, int n)->s8v{
    int rB = wn*64 + n*16 + l15;
    return *(const s8v*)(S + 16384 + buf*8192 + rB*32 + ((l16 ^ (rB & 3))*8));
  };

  // prologue: stage K-tile 0 (4 loads/thread)
  stA(0, 0); stB(0, 0);

  const int NT = DIM / 32;   // 96
  for (int t = 0; t < NT; t++){
    int cur = t & 1, nxt = cur ^ 1;
    bool pf = (t + 1 < NT);
    if (pf){
      int kt1 = (t + 1) * 32;
      stA(nxt, kt1); stB(nxt, kt1);
      asm volatile("s_waitcnt vmcnt(4)" ::: "memory");   // keep t+1's 4 in flight
    } else {
      asm volatile("s_waitcnt vmcnt(0)" ::: "memory");
    }
    __builtin_amdgcn_s_barrier();   // tile-t visible

    #pragma unroll
    for (int n = 0; n < 4; n++) bfr[n] = rdB(cur, n);
    #pragma unroll
    for (int m = 0; m < 8; m++) af[m] = rdA(cur, m);
    __builtin_amdgcn_s_setprio(1);
    #pragma unroll
    for (int m = 0; m < 8; m++)
      #pragma unroll
      for (int n = 0; n < 4; n++)
        acc[m][n] = MFMA(af[m], bfr[n], acc[m][n]);
    __builtin_amdgcn_s_setprio(0);
    __builtin_amdgcn_s_barrier();   // all waves done reading cur
  }

  // ---- ip path: store fp32 rows<64 ----
  if (is_ip){
    float* outp = z2 ? ipv_pre : ipk_pre;
    if (wm == 0){
      #pragma unroll
      for (int m = 0; m < 4; m++)
        #pragma unroll
        for (int j = 0; j < 4; j++){
          int row = m*16 + l16*4 + j;
          #pragma unroll
          for (int n = 0; n < 4; n++)
            outp[(size_t)row*DIM + n0 + wn*64 + n*16 + l15] = acc[m][n][j];
        }
    }
    return;
  }

  // ---- LoRA extra K-tile (K=64) for k/v rows >= 2048: S split 32KB/32KB ----
  if (z >= 1 && m0 >= BLK){
    const unsigned short* dwn = downb + (size_t)(z-1)*CONDN*64 + (size_t)(m0 - BLK)*64;
    const unsigned short* up  = (z == 1) ? upk : upv;
    #pragma unroll
    for (int i = 0; i < 4; i++){
      int p = i*512 + tid;            // p in [0,2048): row=p>>3, cc=p&7
      int row = p >> 3, cc = p & 7, gc = cc ^ (row & 7);
      GL16(dwn + (size_t)row*64 + gc*8, S + p*8);
      GL16(up + (size_t)(n0 + row)*64 + gc*8, S + 16384 + p*8);
    }
    asm volatile("s_waitcnt vmcnt(0)" ::: "memory");
    __builtin_amdgcn_s_barrier();
    #pragma unroll
    for (int kk = 0; kk < 2; kk++){
      s8v aL[8], bL[4];
      #pragma unroll
      for (int m = 0; m < 8; m++){
        int rA = wm*128 + m*16 + l15;
        aL[m] = *(const s8v*)(S + rA*64 + ((kk*4 + l16) ^ (rA & 7))*8);
      }
      #pragma unroll
      for (int n = 0; n < 4; n++){
        int rB = wn*64 + n*16 + l15;
        bL[n] = *(const s8v*)(S + 16384 + rB*64 + ((kk*4 + l16) ^ (rB & 7))*8);
      }
      #pragma unroll
      for (int m = 0; m < 8; m++)
        #pragma unroll
        for (int n = 0; n < 4; n++)
          acc[m][n] = MFMA(aL[m], bL[n], acc[m][n]);
    }
  }

  // ---- bias + bf16 store ----
  {
    const float* bias = z == 0 ? bq : (z == 1 ? bk : bv);
    unsigned short* C = z == 0 ? qb : (z == 1 ? kb : vb);
    float bv4[4];
    #pragma unroll
    for (int n = 0; n < 4; n++) bv4[n] = bias[n0 + wn*64 + n*16 + l15];
    #pragma unroll
    for (int m = 0; m < 8; m++)
      #pragma unroll
      for (int j = 0; j < 4; j++){
        int row = m0 + wm*128 + m*16 + l16*4 + j;
        unsigned short* crow = C + (size_t)row*DIM;
        #pragma unroll
        for (int n = 0; n < 4; n++)
          crow[n0 + wn*64 + n*16 + l15] = f2bf(acc[m][n][j] + bv4[n]);
      }
  }
}

// ---------------- rmsnorm + rope (bf16 in) -> bf16 head-major [H][S][HD] ----------------
__global__ __launch_bounds__(256) void norm_rope(const unsigned short* __restrict__ src,
                                                 unsigned short* __restrict__ dst,
                                                 const float* __restrict__ wt,
                                                 const float* __restrict__ rc,
                                                 const float* __restrict__ rs,
                                                 int S, float qscale){
  int tid = threadIdx.x, lane = tid & 63, w = tid >> 6;
  int r = blockIdx.x*4 + w;
  int pos = r % S, h = r / S;
  const unsigned short* x = src + (size_t)pos*DIM + h*HD;
  ushort2 xv2 = *(const ushort2*)(x + 2*lane);
  float x0 = bf2f(xv2.x), x1 = bf2f(xv2.y);
  float ss = x0*x0 + x1*x1;
  #pragma unroll
  for (int o = 1; o < 64; o <<= 1) ss += __shfl_xor(ss, o);
  float rr = rsqrtf(ss*(1.f/128.f) + 1e-6f);
  float y0 = x0*rr*wt[2*lane], y1 = x1*rr*wt[2*lane+1];
  float2 cv = *(const float2*)(rc + (size_t)pos*HD + 2*lane);
  float2 sv = *(const float2*)(rs + (size_t)pos*HD + 2*lane);
  float o0 = (y0*cv.x - y1*sv.x)*qscale;
  float o1 = (y1*cv.y + y0*sv.y)*qscale;
  ushort2 ov; ov.x = f2bf(o0); ov.y = f2bf(o1);
  *(ushort2*)(dst + ((size_t)h*S + pos)*HD + 2*lane) = ov;
}

// ---------------- ip_k rmsnorm (eps 1e-5, no weight) -> bf16 [H][64][HD] ----------------
__global__ __launch_bounds__(256) void ipk_norm_bf(const float* __restrict__ src,
                                                   unsigned short* __restrict__ dst){
  int tid = threadIdx.x, lane = tid & 63, w = tid >> 6;
  int r = blockIdx.x*4 + w;         // r < 64*24
  int pos = r / HEADS, h = r % HEADS;
  const float* x = src + (size_t)pos*DIM + h*HD;
  float2 xv = *(const float2*)(x + 2*lane);
  float ss = xv.x*xv.x + xv.y*xv.y;
  #pragma unroll
  for (int o = 1; o < 64; o <<= 1) ss += __shfl_xor(ss, o);
  float rr = rsqrtf(ss*(1.f/128.f) + 1e-5f);
  ushort2 ov; ov.x = f2bf(xv.x*rr); ov.y = f2bf(xv.y*rr);
  *(ushort2*)(dst + ((size_t)h*NIPN + pos)*HD + 2*lane) = ov;
}

// ---------------- ipv -> bf16 [H][HD][64] transpose ----------------
__global__ __launch_bounds__(256) void ipv_transpose(const float* __restrict__ ipv,
                                                     unsigned short* __restrict__ vt){
  int h = blockIdx.x, tid = threadIdx.x;
  #pragma unroll
  for (int i = 0; i < 32; i++){
    int idx = i*256 + tid;
    int d = idx >> 6, key = idx & 63;
    vt[((size_t)h*HD + d)*64 + key] = f2bf(ipv[(size_t)key*DIM + h*HD + d]);
  }
}

// ---------------- v (bf16) -> Vt bf16 [H][HD][SEQ] transpose ----------------
__global__ __launch_bounds__(256) void v_transpose(const unsigned short* __restrict__ v,
                                                   unsigned short* __restrict__ Vt){
  __shared__ unsigned short t[64][137];
  int h = blockIdx.y, p0 = blockIdx.x*64, tid = threadIdx.x;
  int dcol = tid & 127, prow2 = tid >> 7;
  #pragma unroll
  for (int i = 0; i < 32; i++){
    int pos = i*2 + prow2;
    t[pos][dcol] = v[(size_t)(p0+pos)*DIM + h*HD + dcol];
  }
  __syncthreads();
  int pos = tid & 63, dbase = tid >> 6;
  #pragma unroll
  for (int i = 0; i < 32; i++){
    int d = i*4 + dbase;
    Vt[((size_t)h*HD + d)*SEQN + p0 + pos] = t[pos][d];
  }
}

// ---------------- IP attention (MFMA): 2048 q x 64 keys per head, exact softmax ----------------
__global__ __launch_bounds__(256) void ip_attn_m(const unsigned short* __restrict__ qb,
                                                 const unsigned short* __restrict__ ipk_bf,
                                                 const unsigned short* __restrict__ ipv_t,
                                                 float* __restrict__ out){
  __shared__ unsigned short Ks[64*HD];
  __shared__ unsigned short Vs[HD*64];
  __shared__ unsigned short Ps[4][16*64];
  int tid = threadIdx.x, lane = tid & 63, w = tid >> 6;
  int l15 = lane & 15, l16 = lane >> 4;
  int h = blockIdx.y;
  int q0 = blockIdx.x*64 + w*16;
  const unsigned short* Kh = ipk_bf + (size_t)h*NIPN*HD;
  const unsigned short* Vh = ipv_t + (size_t)h*HD*NIPN;

  #pragma unroll
  for (int i = 0; i < 4; i++){
    int p = i*256 + tid;
    int row = p >> 4, cc = p & 15;
    int gc = cc ^ (row & 7);
    GL16(Kh + (size_t)row*HD + gc*8, Ks + p*8);
  }
  #pragma unroll
  for (int i = 0; i < 4; i++){
    int p = i*256 + tid;
    int row = p >> 3, cc = p & 7;
    int gc = cc ^ (row & 7);
    GL16(Vh + (size_t)row*64 + gc*8, Vs + p*8);
  }

  s8v qf[4];
  #pragma unroll
  for (int kf = 0; kf < 4; kf++)
    qf[kf] = *(const s8v*)(qb + (size_t)(q0 + l15)*DIM + h*HD + kf*32 + l16*8);
  __syncthreads();

  fx4 s[4] = {};
  #pragma unroll
  for (int ct = 0; ct < 4; ct++){
    #pragma unroll
    for (int kk = 0; kk < 4; kk++){
      int row = ct*16 + l15;
      int c = (kk*4 + l16) ^ (row & 7);
      s8v b = *(const s8v*)(Ks + row*HD + c*8);
      s[ct] = MFMA(qf[kk], b, s[ct]);
    }
  }
  const float SC = 0.08838834764831845f;
  float lrow[4];
  #pragma unroll
  for (int j = 0; j < 4; j++){
    #pragma unroll
    for (int ct = 0; ct < 4; ct++) s[ct][j] *= SC;
    float v = fmaxf(fmaxf(s[0][j], s[1][j]), fmaxf(s[2][j], s[3][j]));
    #pragma unroll
    for (int o2 = 1; o2 < 16; o2 <<= 1) v = fmaxf(v, __shfl_xor(v, o2));
    float sum = 0.f;
    #pragma unroll
    for (int ct = 0; ct < 4; ct++){
      float p = __expf(s[ct][j] - v);
      s[ct][j] = p;
      sum += p;
    }
    #pragma unroll
    for (int o2 = 1; o2 < 16; o2 <<= 1) sum += __shfl_xor(sum, o2);
    lrow[j] = sum;
  }

  #pragma unroll
  for (int ct = 0; ct < 4; ct++)
    #pragma unroll
    for (int j = 0; j < 4; j++){
      int row = l16*4 + j;
      int cidx = ct*16 + l15;
      Ps[w][row*64 + (((cidx>>3) ^ (row&7))<<3) + (cidx&7)] = f2bf(s[ct][j]);
    }
  asm volatile("s_waitcnt lgkmcnt(0)" ::: "memory");
  s8v pa[2];
  #pragma unroll
  for (int kk = 0; kk < 2; kk++){
    int c = (kk*4 + l16) ^ (l15 & 7);
    pa[kk] = *(const s8v*)(&Ps[w][l15*64 + c*8]);
  }
  fx4 o[8] = {};
  #pragma unroll
  for (int nt = 0; nt < 8; nt++){
    #pragma unroll
    for (int kk = 0; kk < 2; kk++){
      int row = nt*16 + l15;
      int c = (kk*4 + l16) ^ (row & 7);
      s8v bv = *(const s8v*)(Vs + row*64 + c*8);
      o[nt] = MFMA(pa[kk], bv, o[nt]);
    }
  }
  #pragma unroll
  for (int nt = 0; nt < 8; nt++)
    #pragma unroll
    for (int j = 0; j < 4; j++){
      int row = q0 + l16*4 + j;
      int d = nt*16 + l15;
      out[(size_t)row*DIM + h*HD + d] = o[nt][j] / lrow[j];
    }
}

// ---------------- main flash attention, split-K x2, 8-wave blocks, XCD-chunked ----------------
#define QB 128
#define KVB 64
#define PSTR 72
__global__ __launch_bounds__(512, 4) void flash_attn_split(const unsigned short* __restrict__ Qn,
                                                           const unsigned short* __restrict__ Kn,
                                                           const unsigned short* __restrict__ Vt,
                                                           float* __restrict__ po0,
                                                           float* __restrict__ po1,
                                                           float* __restrict__ pm,
                                                           float* __restrict__ pl){
  __shared__ unsigned short Ks[KVB*HD];
  __shared__ unsigned short Vs[HD*KVB];
  __shared__ unsigned short Ps[8][16*PSTR];
  int tid = threadIdx.x, lane = tid & 63, w = tid >> 6;
  int l15 = lane & 15, l16 = lane >> 4;
  int b = blockIdx.x;
  int swz = (b & 7) * 96 + (b >> 3);
  int sp = swz / 384;
  int rem = swz - sp*384;
  int h = rem >> 4;
  int qt = rem & 15;
  int q0 = qt*QB + w*16;
  const unsigned short* Qh = Qn + (size_t)h*BLK*HD;
  const unsigned short* Kh = Kn + (size_t)h*SEQN*HD;
  const unsigned short* Vh = Vt + (size_t)h*HD*SEQN;
  const int kvbase = sp * (SEQN/2);
  const int NT = (SEQN/2) / KVB;

  s8v qf[4];
  #pragma unroll
  for (int kf = 0; kf < 4; kf++)
    qf[kf] = *(const s8v*)(Qh + (size_t)(q0 + l15)*HD + kf*32 + l16*8);

  fx4 o[8] = {};
  float mrow[4], lrow[4];
  #pragma unroll
  for (int j = 0; j < 4; j++){ mrow[j] = -1e30f; lrow[j] = 0.f; }

  for (int t = 0; t < NT; t++){
    int kv0 = kvbase + t*KVB;
    #pragma unroll
    for (int i = 0; i < 2; i++){
      int p = i*512 + tid;
      int row = p >> 4, cc = p & 15;
      int gc = cc ^ (row & 7);
      GL16(Kh + (size_t)(kv0+row)*HD + gc*8, Ks + p*8);
    }
    #pragma unroll
    for (int i = 0; i < 2; i++){
      int p = i*512 + tid;
      int row = p >> 3, cc = p & 7;
      int gc = cc ^ (row & 7);
      GL16(Vh + (size_t)row*SEQN + kv0 + gc*8, Vs + p*8);
    }
    __syncthreads();

    fx4 s[4] = {};
    #pragma unroll
    for (int ct = 0; ct < 4; ct++){
      #pragma unroll
      for (int kk = 0; kk < 4; kk++){
        int row = ct*16 + l15;
        int c = (kk*4 + l16) ^ (row & 7);
        s8v bb = *(const s8v*)(Ks + row*HD + c*8);
        s[ct] = MFMA(qf[kk], bb, s[ct]);
      }
    }
    float pmax[4], rssum[4];
    #pragma unroll
    for (int j = 0; j < 4; j++){
      float v = fmaxf(fmaxf(s[0][j], s[1][j]), fmaxf(s[2][j], s[3][j]));
      #pragma unroll
      for (int o2 = 1; o2 < 16; o2 <<= 1) v = fmaxf(v, __shfl_xor(v, o2));
      pmax[j] = v;
      rssum[j] = 0.f;
    }
    float need = 0.f;
    #pragma unroll
    for (int j = 0; j < 4; j++) need = fmaxf(need, pmax[j] - mrow[j]);
    if (__any(need > 8.f)){
      float alpha[4];
      #pragma unroll
      for (int j = 0; j < 4; j++){
        float mnew = fmaxf(mrow[j], pmax[j]);
        alpha[j] = __expf(mrow[j] - mnew);
        mrow[j] = mnew;
      }
      #pragma unroll
      for (int nt = 0; nt < 8; nt++)
        #pragma unroll
        for (int j = 0; j < 4; j++) o[nt][j] *= alpha[j];
      #pragma unroll
      for (int j = 0; j < 4; j++) lrow[j] *= alpha[j];
    }
    #pragma unroll
    for (int ct = 0; ct < 4; ct++)
      #pragma unroll
      for (int j = 0; j < 4; j++){
        float p = __expf(s[ct][j] - mrow[j]);
        s[ct][j] = p;
        rssum[j] += p;
      }
    #pragma unroll
    for (int j = 0; j < 4; j++){
      #pragma unroll
      for (int o2 = 1; o2 < 16; o2 <<= 1) rssum[j] += __shfl_xor(rssum[j], o2);
      lrow[j] += rssum[j];
    }

    #pragma unroll
    for (int ct = 0; ct < 4; ct++)
      #pragma unroll
      for (int j = 0; j < 4; j++){
        int row = l16*4 + j;
        int cidx = ct*16 + l15;
        Ps[w][row*PSTR + cidx] = f2bf(s[ct][j]);
      }
    asm volatile("s_waitcnt lgkmcnt(0)" ::: "memory");
    s8v pa[2];
    #pragma unroll
    for (int kk = 0; kk < 2; kk++)
      pa[kk] = *(const s8v*)(&Ps[w][l15*PSTR + (kk*4 + l16)*8]);
    #pragma unroll
    for (int nt = 0; nt < 8; nt++){
      #pragma unroll
      for (int kk = 0; kk < 2; kk++){
        int row = nt*16 + l15;
        int c = (kk*4 + l16) ^ (row & 7);
        s8v bvv = *(const s8v*)(Vs + row*KVB + c*8);
        o[nt] = MFMA(pa[kk], bvv, o[nt]);
      }
    }
    __syncthreads();
  }

  float* pop = sp ? po1 : po0;
  #pragma unroll
  for (int nt = 0; nt < 8; nt++)
    #pragma unroll
    for (int j = 0; j < 4; j++){
      int row = q0 + l16*4 + j;
      int d = nt*16 + l15;
      pop[((size_t)h*BLK + row)*HD + d] = o[nt][j];
    }
  if (l15 == 0){
    #pragma unroll
    for (int j = 0; j < 4; j++){
      int row = q0 + l16*4 + j;
      pm[(size_t)sp*HEADS*BLK + h*BLK + row] = mrow[j];
      pl[(size_t)sp*HEADS*BLK + h*BLK + row] = lrow[j];
    }
  }
}

// ---------------- merge the two split-K halves into out (+=) ----------------
__global__ __launch_bounds__(256) void flash_merge(const float* __restrict__ po0,
                                                   const float* __restrict__ po1,
                                                   const float* __restrict__ pm,
                                                   const float* __restrict__ pl,
                                                   float* __restrict__ out){
  int tid = threadIdx.x, lane = tid & 63, w = tid >> 6;
  int r = blockIdx.x*4 + w;
  int h = r >> 11, pos = r & 2047;
  float m0 = pm[r], m1 = pm[HEADS*BLK + r];
  float l0 = pl[r], l1 = pl[HEADS*BLK + r];
  float mx = fmaxf(m0, m1);
  float a0 = __expf(m0 - mx), a1 = __expf(m1 - mx);
  float li = 1.f / (l0*a0 + l1*a1);
  float s0 = a0*li, s1 = a1*li;
  size_t base = ((size_t)h*BLK + pos)*HD + 2*lane;
  float2 x0 = *(const float2*)(po0 + base);
  float2 x1 = *(const float2*)(po1 + base);
  float* op = out + (size_t)pos*DIM + h*HD + 2*lane;
  float2 cv = *(const float2*)op;
  cv.x += x0.x*s0 + x1.x*s1;
  cv.y += x0.y*s0 + x1.y*s1;
  *(float2*)op = cv;
}

extern "C" void kernel_launch(void* const* d_in, const int* in_sizes, int n_in,
                              void* d_out, int out_size, void* d_ws, size_t ws_size,
                              hipStream_t stream){
  (void)in_sizes; (void)n_in; (void)out_size;
  const float* hs       = (const float*)d_in[0];
  const float* image_emb= (const float*)d_in[1];
  const float* rope_cos = (const float*)d_in[2];
  const float* rope_sin = (const float*)d_in[3];
  const float* wq = (const float*)d_in[4];
  const float* bq = (const float*)d_in[5];
  const float* wk = (const float*)d_in[6];
  const float* bk = (const float*)d_in[7];
  const float* wv = (const float*)d_in[8];
  const float* bv = (const float*)d_in[9];
  const float* norm_q_w = (const float*)d_in[10];
  const float* norm_k_w = (const float*)d_in[11];
  const float* k_down = (const float*)d_in[14];
  const float* k_up   = (const float*)d_in[15];
  const float* v_down = (const float*)d_in[16];
  const float* v_up   = (const float*)d_in[17];
  const float* wk_ip  = (const float*)d_in[18];
  const float* wv_ip  = (const float*)d_in[19];
  float* out = (float*)d_out;

  char* ws = (char*)d_ws;
  size_t off = 0;
  auto alloc = [&](size_t bytes){ void* p = ws + off; off += (bytes + 255) & ~(size_t)255; return p; };
  unsigned short* hs_bf = (unsigned short*)alloc((size_t)SEQN*DIM*2);
  unsigned short* ie_bf = (unsigned short*)alloc((size_t)NIPN*DIM*2);
  unsigned short* w_bf[5];
  for (int i = 0; i < 5; i++) w_bf[i] = (unsigned short*)alloc((size_t)DIM*DIM*2);
  unsigned short* lw_bf[4];   // k_down, v_down, k_up, v_up
  for (int i = 0; i < 4; i++) lw_bf[i] = (unsigned short*)alloc((size_t)RANKN*DIM*2);
  unsigned short* downb = (unsigned short*)alloc((size_t)2*CONDN*RANKN*2);
  unsigned short* qb = (unsigned short*)alloc((size_t)BLK*DIM*2);
  unsigned short* kb = (unsigned short*)alloc((size_t)SEQN*DIM*2);
  unsigned short* vb = (unsigned short*)alloc((size_t)SEQN*DIM*2);
  float* ipk_pre = (float*)alloc((size_t)NIPN*DIM*4);
  float* ipv_pre = (float*)alloc((size_t)NIPN*DIM*4);
  unsigned short* ipk_bf = (unsigned short*)alloc((size_t)HEADS*NIPN*HD*2);
  unsigned short* ipv_t  = (unsigned short*)alloc((size_t)HEADS*HD*NIPN*2);
  float* po0 = (float*)alloc((size_t)HEADS*BLK*HD*4);
  float* po1 = (float*)alloc((size_t)HEADS*BLK*HD*4);
  float* pm  = (float*)alloc((size_t)2*HEADS*BLK*4);
  float* pl  = (float*)alloc((size_t)2*HEADS*BLK*4);
  if (off > ws_size) return;

  // Aliases onto dead buffers (weights consumed by gemm_256 before these are written):
  unsigned short* Qn = w_bf[0];
  unsigned short* Kn = w_bf[1];
  unsigned short* Vt = w_bf[2];

  int n4;
  n4 = SEQN*DIM/4;
  cvt_f32_bf16<<<(n4+255)/256, 256, 0, stream>>>(hs, hs_bf, n4);
  n4 = NIPN*DIM/4;
  cvt_f32_bf16<<<(n4+255)/256, 256, 0, stream>>>(image_emb, ie_bf, n4);

  n4 = DIM*DIM/4;
  cvt_f32_bf16<<<(n4+255)/256, 256, 0, stream>>>(wq, w_bf[0], n4);
  cvt_f32_bf16<<<(n4+255)/256, 256, 0, stream>>>(wk, w_bf[1], n4);
  cvt_f32_bf16<<<(n4+255)/256, 256, 0, stream>>>(wv, w_bf[2], n4);
  cvt_f32_bf16<<<(n4+255)/256, 256, 0, stream>>>(wk_ip, w_bf[3], n4);
  cvt_f32_bf16<<<(n4+255)/256, 256, 0, stream>>>(wv_ip, w_bf[4], n4);

  n4 = RANKN*DIM/4;
  cvt_f32_bf16<<<(n4+255)/256, 256, 0, stream>>>(k_down, lw_bf[0], n4);
  cvt_f32_bf16<<<(n4+255)/256, 256, 0, stream>>>(v_down, lw_bf[1], n4);
  cvt_f32_bf16<<<(n4+255)/256, 256, 0, stream>>>(k_up,   lw_bf[2], n4);
  cvt_f32_bf16<<<(n4+255)/256, 256, 0, stream>>>(v_up,   lw_bf[3], n4);

  lora_down_g<<<dim3(1, CONDN/128, 2), 256, 0, stream>>>(hs_bf + (size_t)BLK*DIM,
      lw_bf[0], lw_bf[1], downb);

  gemm_256<<<408, 512, 0, stream>>>(hs_bf, ie_bf,
      w_bf[0], w_bf[1], w_bf[2], w_bf[3], w_bf[4],
      bq, bk, bv, downb, lw_bf[2], lw_bf[3],
      qb, kb, vb, ipk_pre, ipv_pre);

  ipk_norm_bf<<<(NIPN*HEADS)/4, 256, 0, stream>>>(ipk_pre, ipk_bf);
  ipv_transpose<<<HEADS, 256, 0, stream>>>(ipv_pre, ipv_t);

  const float SC = 0.08838834764831845f;
  norm_rope<<<(BLK*HEADS)/4, 256, 0, stream>>>(qb, Qn, norm_q_w, rope_cos, rope_sin, BLK, SC);
  norm_rope<<<(SEQN*HEADS)/4, 256, 0, stream>>>(kb, Kn, norm_k_w, rope_cos, rope_sin, SEQN, 1.0f);
  v_transpose<<<dim3(SEQN/64, HEADS), 256, 0, stream>>>(vb, Vt);

  ip_attn_m<<<dim3(BLK/64, HEADS), 256, 0, stream>>>(qb, ipk_bf, ipv_t, out);
  flash_attn_split<<<768, 512, 0, stream>>>(Qn, Kn, Vt, po0, po1, pm, pl);
  flash_merge<<<(HEADS*BLK)/4, 256, 0, stream>>>(po0, po1, pm, pl, out);
}

// Round 11
// 527.827 us; speedup vs baseline: 3.7470x; 3.7470x over previous
//
#include <hip/hip_runtime.h>
#include <stdint.h>

#define DIM 3072
#define HEADS 24
#define HD 128
#define RANKN 64
#define CONDN 1024
#define BLK 2048
#define SEQN 3072
#define NIPN 64

typedef __attribute__((ext_vector_type(8))) short s8v;
typedef __attribute__((ext_vector_type(4))) float fx4;

static __device__ __forceinline__ unsigned short f2bf(float f){
  union{float f; unsigned u;} v; v.f=f;
  unsigned r = v.u + 0x7FFFu + ((v.u>>16)&1u);
  return (unsigned short)(r>>16);
}
static __device__ __forceinline__ float bf2f(unsigned short b){
  union{unsigned u; float f;} v; v.u = ((unsigned)b) << 16;
  return v.f;
}

#define GL16(g,l) __builtin_amdgcn_global_load_lds((const __attribute__((address_space(1))) void*)(g), (__attribute__((address_space(3))) void*)(l), 16, 0, 0)
#define MFMA(a,b,c) __builtin_amdgcn_mfma_f32_16x16x32_bf16((a),(b),(c),0,0,0)

// ---------------- fp32 -> bf16 convert (4 elems/thread) ----------------
__global__ __launch_bounds__(256) void cvt_f32_bf16(const float* __restrict__ src,
                                                    unsigned short* __restrict__ dst, int n4){
  int i = blockIdx.x*256 + threadIdx.x;
  if (i < n4){
    float4 v = ((const float4*)src)[i];
    ushort4 o;
    o.x = f2bf(v.x); o.y = f2bf(v.y); o.z = f2bf(v.z); o.w = f2bf(v.w);
    ((ushort4*)dst)[i] = o;
  }
}

// ---------------- batched fp32 -> bf16 for 5 weight matrices ----------------
__global__ __launch_bounds__(256) void cvt_w5(const float* __restrict__ s0, const float* __restrict__ s1,
                                              const float* __restrict__ s2, const float* __restrict__ s3,
                                              const float* __restrict__ s4,
                                              unsigned short* __restrict__ d0, unsigned short* __restrict__ d1,
                                              unsigned short* __restrict__ d2, unsigned short* __restrict__ d3,
                                              unsigned short* __restrict__ d4){
  int z = blockIdx.y;
  const float* src = z==0?s0:(z==1?s1:(z==2?s2:(z==3?s3:s4)));
  unsigned short* dst = z==0?d0:(z==1?d1:(z==2?d2:(z==3?d3:d4)));
  int i = blockIdx.x*256 + threadIdx.x;   // n4 = DIM*DIM/4
  float4 v = ((const float4*)src)[i];
  ushort4 o;
  o.x = f2bf(v.x); o.y = f2bf(v.y); o.z = f2bf(v.z); o.w = f2bf(v.w);
  ((ushort4*)dst)[i] = o;
}

// ---------------- batched fp32 -> bf16 for 4 lora weights ----------------
__global__ __launch_bounds__(256) void cvt_w4(const float* __restrict__ s0, const float* __restrict__ s1,
                                              const float* __restrict__ s2, const float* __restrict__ s3,
                                              unsigned short* __restrict__ d0, unsigned short* __restrict__ d1,
                                              unsigned short* __restrict__ d2, unsigned short* __restrict__ d3){
  int z = blockIdx.y;
  const float* src = z==0?s0:(z==1?s1:(z==2?s2:s3));
  unsigned short* dst = z==0?d0:(z==1?d1:(z==2?d2:d3));
  int i = blockIdx.x*256 + threadIdx.x;   // n4 = RANKN*DIM/4
  float4 v = ((const float4*)src)[i];
  ushort4 o;
  o.x = f2bf(v.x); o.y = f2bf(v.y); o.z = f2bf(v.z); o.w = f2bf(v.w);
  ((ushort4*)dst)[i] = o;
}

// ---------------- LoRA down (MFMA): downb[z][1024][64], z=0:k 1:v ----------------
__global__ __launch_bounds__(256) void lora_down_g(const unsigned short* __restrict__ A,
                                                   const unsigned short* __restrict__ D0,
                                                   const unsigned short* __restrict__ D1,
                                                   unsigned short* __restrict__ outb){
  __shared__ unsigned short As[128*64];
  __shared__ unsigned short Bs[64*64];
  int tid = threadIdx.x, lane = tid & 63, w = tid >> 6;
  int l15 = lane & 15, l16 = lane >> 4;
  int z = blockIdx.z;
  int m0 = blockIdx.y * 128;
  const unsigned short* Dw = z ? D1 : D0;
  int wr = w * 32;
  fx4 acc[2][4] = {};
  for (int kt = 0; kt < DIM; kt += 64){
    #pragma unroll
    for (int i = 0; i < 4; i++){
      int p = i*256 + tid;
      int row = p >> 3, cc = p & 7;
      int gc = cc ^ (row & 7);
      GL16(A + (size_t)(m0+row)*DIM + kt + gc*8, As + p*8);
    }
    #pragma unroll
    for (int i = 0; i < 2; i++){
      int p = i*256 + tid;
      int row = p >> 3, cc = p & 7;
      int gc = cc ^ (row & 7);
      GL16(Dw + (size_t)row*DIM + kt + gc*8, Bs + p*8);
    }
    __syncthreads();
    #pragma unroll
    for (int kk = 0; kk < 2; kk++){
      s8v af[2], bfr[4];
      #pragma unroll
      for (int t = 0; t < 2; t++){
        int rowa = wr + t*16 + l15;
        int ca = (kk*4 + l16) ^ (rowa & 7);
        af[t] = *(const s8v*)(As + rowa*64 + ca*8);
      }
      #pragma unroll
      for (int t = 0; t < 4; t++){
        int rowb = t*16 + l15;
        int cb = (kk*4 + l16) ^ (rowb & 7);
        bfr[t] = *(const s8v*)(Bs + rowb*64 + cb*8);
      }
      #pragma unroll
      for (int mt = 0; mt < 2; mt++)
        #pragma unroll
        for (int nt = 0; nt < 4; nt++)
          acc[mt][nt] = MFMA(af[mt], bfr[nt], acc[mt][nt]);
    }
    __syncthreads();
  }
  #pragma unroll
  for (int mt = 0; mt < 2; mt++)
    #pragma unroll
    for (int j = 0; j < 4; j++){
      int row = m0 + wr + mt*16 + l16*4 + j;
      #pragma unroll
      for (int nt = 0; nt < 4; nt++){
        int col = nt*16 + l15;
        outb[((size_t)z*CONDN + row)*64 + col] = f2bf(acc[mt][nt][j]);
      }
    }
}

// ---------------- 256x256 QKV GEMM: 2-barrier dbuf pipeline, counted vmcnt (R9 verified) ----------------
// 408 blocks x 512 threads. id: [0,96) q | [96,240) k | [240,384) v | [384,408) ip.
__global__ __launch_bounds__(512, 2) void gemm_256(
    const unsigned short* __restrict__ hs_bf,
    const unsigned short* __restrict__ ie_bf,
    const unsigned short* __restrict__ Wq,
    const unsigned short* __restrict__ Wk,
    const unsigned short* __restrict__ Wv,
    const unsigned short* __restrict__ Wik,
    const unsigned short* __restrict__ Wiv,
    const float* __restrict__ bq, const float* __restrict__ bk, const float* __restrict__ bv,
    const unsigned short* __restrict__ downb,
    const unsigned short* __restrict__ upk,
    const unsigned short* __restrict__ upv,
    unsigned short* __restrict__ qb, unsigned short* __restrict__ kb, unsigned short* __restrict__ vb,
    float* __restrict__ ipk_pre, float* __restrict__ ipv_pre)
{
  __shared__ unsigned short Ab[2][16384];   // 64 KB
  __shared__ unsigned short Bb[2][16384];   // 64 KB
  int tid = threadIdx.x, lane = tid & 63, w = tid >> 6;
  int wm = w >> 2, wn = w & 3;
  int l15 = lane & 15, l16 = lane >> 4;

  int b = blockIdx.x;
  int id = (b & 7) * 51 + (b >> 3);        // bijective XCD-chunked swizzle (408 = 8*51)
  int z, mt, ntile;
  if (id < 96){ z = 0; mt = id / 12; ntile = id % 12; }
  else if (id < 240){ z = 1; int r = id - 96; mt = r / 12; ntile = r % 12; }
  else if (id < 384){ z = 2; int r = id - 240; mt = r / 12; ntile = r % 12; }
  else { z = 3; int r = id - 384; mt = r / 12; ntile = r % 12; }
  const bool is_ip = (z == 3);
  int z2 = is_ip ? mt : 0;
  int m0 = is_ip ? 0 : mt * 256;
  int n0 = ntile * 256;
  const unsigned short* A = is_ip ? ie_bf : hs_bf;
  const unsigned short* B = is_ip ? (z2 ? Wiv : Wik)
                                  : (z == 0 ? Wq : (z == 1 ? Wk : Wv));

  fx4 acc[8][4] = {};
  s8v af[8], bfr[8];

  auto stA = [&](int buf, int half, int kt){
    #pragma unroll
    for (int i = 0; i < 2; i++){
      int p = i*512 + tid;
      int row = p >> 3, cc = p & 7, gc = cc ^ (row & 7);
      int ar = m0 + half*128 + row;
      if (is_ip && ar > 63) ar = 63;
      GL16(A + (size_t)ar*DIM + kt + gc*8, &Ab[buf][half*8192 + p*8]);
    }
  };
  auto stB = [&](int buf, int half, int kt){
    #pragma unroll
    for (int i = 0; i < 2; i++){
      int p = i*512 + tid;
      int row = p >> 3, cc = p & 7, gc = cc ^ (row & 7);
      GL16(B + (size_t)(n0 + half*128 + row)*DIM + kt + gc*8, &Bb[buf][half*8192 + p*8]);
    }
  };
  auto rdA = [&](int buf, int m, int kk)->s8v{
    int rl = m*16 + l15;
    return *(const s8v*)(&Ab[buf][wm*8192 + rl*64 + ((kk*4 + l16) ^ (rl & 7))*8]);
  };
  auto rdB = [&](int buf, int n, int kk)->s8v{
    int rB = wn*64 + n*16 + l15;
    return *(const s8v*)(&Bb[buf][(rB >> 7)*8192 + (rB & 127)*64 + ((kk*4 + l16) ^ (rB & 7))*8]);
  };

  // prologue: stage K-tile 0 (8 loads/wave)
  stA(0,0,0); stA(0,1,0); stB(0,0,0); stB(0,1,0);

  const int NT = DIM / 64;   // 48
  for (int t = 0; t < NT; t++){
    int cur = t & 1, nxt = cur ^ 1;
    bool pf = (t + 1 < NT);
    if (pf){
      int kt1 = (t + 1) * 64;
      stA(nxt, 0, kt1); stA(nxt, 1, kt1);
      stB(nxt, 0, kt1); stB(nxt, 1, kt1);
      asm volatile("s_waitcnt vmcnt(8)" ::: "memory");   // keep the 8 new in flight
    } else {
      asm volatile("s_waitcnt vmcnt(0)" ::: "memory");
    }
    __builtin_amdgcn_s_barrier();   // tile-t data visible to all waves

    // free-running quadrants (reads hit cur only; stages write nxt only)
    #pragma unroll
    for (int m = 0; m < 4; m++){ af[m*2] = rdA(cur,m,0); af[m*2+1] = rdA(cur,m,1); }
    #pragma unroll
    for (int n = 0; n < 2; n++){ bfr[n*2] = rdB(cur,n,0); bfr[n*2+1] = rdB(cur,n,1); }
    __builtin_amdgcn_s_setprio(1);
    #pragma unroll
    for (int m = 0; m < 4; m++)
      #pragma unroll
      for (int n = 0; n < 2; n++){
        acc[m][n] = MFMA(af[m*2],   bfr[n*2],   acc[m][n]);
        acc[m][n] = MFMA(af[m*2+1], bfr[n*2+1], acc[m][n]);
      }
    __builtin_amdgcn_s_setprio(0);
    #pragma unroll
    for (int n = 2; n < 4; n++){ bfr[n*2] = rdB(cur,n,0); bfr[n*2+1] = rdB(cur,n,1); }
    __builtin_amdgcn_s_setprio(1);
    #pragma unroll
    for (int m = 0; m < 4; m++)
      #pragma unroll
      for (int n = 2; n < 4; n++){
        acc[m][n] = MFMA(af[m*2],   bfr[n*2],   acc[m][n]);
        acc[m][n] = MFMA(af[m*2+1], bfr[n*2+1], acc[m][n]);
      }
    __builtin_amdgcn_s_setprio(0);
    #pragma unroll
    for (int m = 4; m < 8; m++){ af[(m-4)*2] = rdA(cur,m,0); af[(m-4)*2+1] = rdA(cur,m,1); }
    __builtin_amdgcn_s_setprio(1);
    #pragma unroll
    for (int m = 4; m < 8; m++)
      #pragma unroll
      for (int n = 2; n < 4; n++){
        acc[m][n] = MFMA(af[(m-4)*2],   bfr[n*2],   acc[m][n]);
        acc[m][n] = MFMA(af[(m-4)*2+1], bfr[n*2+1], acc[m][n]);
      }
    #pragma unroll
    for (int m = 4; m < 8; m++)
      #pragma unroll
      for (int n = 0; n < 2; n++){
        acc[m][n] = MFMA(af[(m-4)*2],   bfr[n*2],   acc[m][n]);
        acc[m][n] = MFMA(af[(m-4)*2+1], bfr[n*2+1], acc[m][n]);
      }
    __builtin_amdgcn_s_setprio(0);
    __builtin_amdgcn_s_barrier();   // all done reading cur before it is re-staged
  }

  // ---- ip path: store fp32 rows<64 ----
  if (is_ip){
    float* outp = z2 ? ipv_pre : ipk_pre;
    if (wm == 0){
      #pragma unroll
      for (int m = 0; m < 4; m++)
        #pragma unroll
        for (int j = 0; j < 4; j++){
          int row = m*16 + l16*4 + j;
          #pragma unroll
          for (int n = 0; n < 4; n++)
            outp[(size_t)row*DIM + n0 + wn*64 + n*16 + l15] = acc[m][n][j];
        }
    }
    return;
  }

  // ---- LoRA extra K-tile for k/v rows >= 2048 ----
  if (z >= 1 && m0 >= BLK){
    const unsigned short* dwn = downb + (size_t)(z-1)*CONDN*64 + (size_t)(m0 - BLK)*64;
    const unsigned short* up  = (z == 1) ? upk : upv;
    #pragma unroll
    for (int i = 0; i < 4; i++){
      int p = i*512 + tid;
      int row = p >> 3, cc = p & 7, gc = cc ^ (row & 7);
      GL16(dwn + (size_t)row*64 + gc*8, &Ab[0][p*8]);
      GL16(up + (size_t)(n0 + row)*64 + gc*8, &Bb[0][p*8]);
    }
    asm volatile("s_waitcnt vmcnt(0)" ::: "memory");
    __builtin_amdgcn_s_barrier();
    #pragma unroll
    for (int kk = 0; kk < 2; kk++){
      s8v aL[8], bL[4];
      #pragma unroll
      for (int m = 0; m < 8; m++){
        int rA = wm*128 + m*16 + l15;
        aL[m] = *(const s8v*)(&Ab[0][rA*64 + ((kk*4 + l16) ^ (rA & 7))*8]);
      }
      #pragma unroll
      for (int n = 0; n < 4; n++){
        int rB = wn*64 + n*16 + l15;
        bL[n] = *(const s8v*)(&Bb[0][rB*64 + ((kk*4 + l16) ^ (rB & 7))*8]);
      }
      #pragma unroll
      for (int m = 0; m < 8; m++)
        #pragma unroll
        for (int n = 0; n < 4; n++)
          acc[m][n] = MFMA(aL[m], bL[n], acc[m][n]);
    }
  }

  // ---- bias + bf16 store ----
  {
    const float* bias = z == 0 ? bq : (z == 1 ? bk : bv);
    unsigned short* C = z == 0 ? qb : (z == 1 ? kb : vb);
    float bv4[4];
    #pragma unroll
    for (int n = 0; n < 4; n++) bv4[n] = bias[n0 + wn*64 + n*16 + l15];
    #pragma unroll
    for (int m = 0; m < 8; m++)
      #pragma unroll
      for (int j = 0; j < 4; j++){
        int row = m0 + wm*128 + m*16 + l16*4 + j;
        unsigned short* crow = C + (size_t)row*DIM;
        #pragma unroll
        for (int n = 0; n < 4; n++)
          crow[n0 + wn*64 + n*16 + l15] = f2bf(acc[m][n][j] + bv4[n]);
      }
  }
}

// ---------------- rmsnorm + rope (bf16 in) -> bf16 head-major [H][S][HD] ----------------
__global__ __launch_bounds__(256) void norm_rope(const unsigned short* __restrict__ src,
                                                 unsigned short* __restrict__ dst,
                                                 const float* __restrict__ wt,
                                                 const float* __restrict__ rc,
                                                 const float* __restrict__ rs,
                                                 int S, float qscale){
  int tid = threadIdx.x, lane = tid & 63, w = tid >> 6;
  int r = blockIdx.x*4 + w;
  int pos = r % S, h = r / S;
  const unsigned short* x = src + (size_t)pos*DIM + h*HD;
  ushort2 xv2 = *(const ushort2*)(x + 2*lane);
  float x0 = bf2f(xv2.x), x1 = bf2f(xv2.y);
  float ss = x0*x0 + x1*x1;
  #pragma unroll
  for (int o = 1; o < 64; o <<= 1) ss += __shfl_xor(ss, o);
  float rr = rsqrtf(ss*(1.f/128.f) + 1e-6f);
  float y0 = x0*rr*wt[2*lane], y1 = x1*rr*wt[2*lane+1];
  float2 cv = *(const float2*)(rc + (size_t)pos*HD + 2*lane);
  float2 sv = *(const float2*)(rs + (size_t)pos*HD + 2*lane);
  float o0 = (y0*cv.x - y1*sv.x)*qscale;
  float o1 = (y1*cv.y + y0*sv.y)*qscale;
  ushort2 ov; ov.x = f2bf(o0); ov.y = f2bf(o1);
  *(ushort2*)(dst + ((size_t)h*S + pos)*HD + 2*lane) = ov;
}

// ---------------- ip_k rmsnorm (eps 1e-5, no weight) -> bf16 [H][64][HD] ----------------
__global__ __launch_bounds__(256) void ipk_norm_bf(const float* __restrict__ src,
                                                   unsigned short* __restrict__ dst){
  int tid = threadIdx.x, lane = tid & 63, w = tid >> 6;
  int r = blockIdx.x*4 + w;         // r < 64*24
  int pos = r / HEADS, h = r % HEADS;
  const float* x = src + (size_t)pos*DIM + h*HD;
  float2 xv = *(const float2*)(x + 2*lane);
  float ss = xv.x*xv.x + xv.y*xv.y;
  #pragma unroll
  for (int o = 1; o < 64; o <<= 1) ss += __shfl_xor(ss, o);
  float rr = rsqrtf(ss*(1.f/128.f) + 1e-5f);
  ushort2 ov; ov.x = f2bf(xv.x*rr); ov.y = f2bf(xv.y*rr);
  *(ushort2*)(dst + ((size_t)h*NIPN + pos)*HD + 2*lane) = ov;
}

// ---------------- ipv -> bf16 [H][HD][64] transpose ----------------
__global__ __launch_bounds__(256) void ipv_transpose(const float* __restrict__ ipv,
                                                     unsigned short* __restrict__ vt){
  int h = blockIdx.x, tid = threadIdx.x;
  #pragma unroll
  for (int i = 0; i < 32; i++){
    int idx = i*256 + tid;
    int d = idx >> 6, key = idx & 63;
    vt[((size_t)h*HD + d)*64 + key] = f2bf(ipv[(size_t)key*DIM + h*HD + d]);
  }
}

// ---------------- v (bf16) -> Vt bf16 [H][HD][SEQ] transpose ----------------
__global__ __launch_bounds__(256) void v_transpose(const unsigned short* __restrict__ v,
                                                   unsigned short* __restrict__ Vt){
  __shared__ unsigned short t[64][137];
  int h = blockIdx.y, p0 = blockIdx.x*64, tid = threadIdx.x;
  int dcol = tid & 127, prow2 = tid >> 7;
  #pragma unroll
  for (int i = 0; i < 32; i++){
    int pos = i*2 + prow2;
    t[pos][dcol] = v[(size_t)(p0+pos)*DIM + h*HD + dcol];
  }
  __syncthreads();
  int pos = tid & 63, dbase = tid >> 6;
  #pragma unroll
  for (int i = 0; i < 32; i++){
    int d = i*4 + dbase;
    Vt[((size_t)h*HD + d)*SEQN + p0 + pos] = t[pos][d];
  }
}

// ---------------- IP attention (MFMA): 2048 q x 64 keys per head, exact softmax ----------------
__global__ __launch_bounds__(256) void ip_attn_m(const unsigned short* __restrict__ qb,
                                                 const unsigned short* __restrict__ ipk_bf,
                                                 const unsigned short* __restrict__ ipv_t,
                                                 float* __restrict__ out){
  __shared__ unsigned short Ks[64*HD];
  __shared__ unsigned short Vs[HD*64];
  __shared__ unsigned short Ps[4][16*64];
  int tid = threadIdx.x, lane = tid & 63, w = tid >> 6;
  int l15 = lane & 15, l16 = lane >> 4;
  int h = blockIdx.y;
  int q0 = blockIdx.x*64 + w*16;
  const unsigned short* Kh = ipk_bf + (size_t)h*NIPN*HD;
  const unsigned short* Vh = ipv_t + (size_t)h*HD*NIPN;

  #pragma unroll
  for (int i = 0; i < 4; i++){
    int p = i*256 + tid;
    int row = p >> 4, cc = p & 15;
    int gc = cc ^ (row & 7);
    GL16(Kh + (size_t)row*HD + gc*8, Ks + p*8);
  }
  #pragma unroll
  for (int i = 0; i < 4; i++){
    int p = i*256 + tid;
    int row = p >> 3, cc = p & 7;
    int gc = cc ^ (row & 7);
    GL16(Vh + (size_t)row*64 + gc*8, Vs + p*8);
  }

  s8v qf[4];
  #pragma unroll
  for (int kf = 0; kf < 4; kf++)
    qf[kf] = *(const s8v*)(qb + (size_t)(q0 + l15)*DIM + h*HD + kf*32 + l16*8);
  __syncthreads();

  fx4 s[4] = {};
  #pragma unroll
  for (int ct = 0; ct < 4; ct++){
    #pragma unroll
    for (int kk = 0; kk < 4; kk++){
      int row = ct*16 + l15;
      int c = (kk*4 + l16) ^ (row & 7);
      s8v b = *(const s8v*)(Ks + row*HD + c*8);
      s[ct] = MFMA(qf[kk], b, s[ct]);
    }
  }
  const float SC = 0.08838834764831845f;
  float lrow[4];
  #pragma unroll
  for (int j = 0; j < 4; j++){
    #pragma unroll
    for (int ct = 0; ct < 4; ct++) s[ct][j] *= SC;
    float v = fmaxf(fmaxf(s[0][j], s[1][j]), fmaxf(s[2][j], s[3][j]));
    #pragma unroll
    for (int o2 = 1; o2 < 16; o2 <<= 1) v = fmaxf(v, __shfl_xor(v, o2));
    float sum = 0.f;
    #pragma unroll
    for (int ct = 0; ct < 4; ct++){
      float p = __expf(s[ct][j] - v);
      s[ct][j] = p;
      sum += p;
    }
    #pragma unroll
    for (int o2 = 1; o2 < 16; o2 <<= 1) sum += __shfl_xor(sum, o2);
    lrow[j] = sum;
  }

  #pragma unroll
  for (int ct = 0; ct < 4; ct++)
    #pragma unroll
    for (int j = 0; j < 4; j++){
      int row = l16*4 + j;
      int cidx = ct*16 + l15;
      Ps[w][row*64 + (((cidx>>3) ^ (row&7))<<3) + (cidx&7)] = f2bf(s[ct][j]);
    }
  asm volatile("s_waitcnt lgkmcnt(0)" ::: "memory");
  s8v pa[2];
  #pragma unroll
  for (int kk = 0; kk < 2; kk++){
    int c = (kk*4 + l16) ^ (l15 & 7);
    pa[kk] = *(const s8v*)(&Ps[w][l15*64 + c*8]);
  }
  fx4 o[8] = {};
  #pragma unroll
  for (int nt = 0; nt < 8; nt++){
    #pragma unroll
    for (int kk = 0; kk < 2; kk++){
      int row = nt*16 + l15;
      int c = (kk*4 + l16) ^ (row & 7);
      s8v bv = *(const s8v*)(Vs + row*64 + c*8);
      o[nt] = MFMA(pa[kk], bv, o[nt]);
    }
  }
  #pragma unroll
  for (int nt = 0; nt < 8; nt++)
    #pragma unroll
    for (int j = 0; j < 4; j++){
      int row = q0 + l16*4 + j;
      int d = nt*16 + l15;
      out[(size_t)row*DIM + h*HD + d] = o[nt][j] / lrow[j];
    }
}

// ---------------- main flash attention, split-K x2, 8-wave blocks, XCD-chunked ----------------
#define QB 128
#define KVB 64
#define PSTR 72
__global__ __launch_bounds__(512, 4) void flash_attn_split(const unsigned short* __restrict__ Qn,
                                                           const unsigned short* __restrict__ Kn,
                                                           const unsigned short* __restrict__ Vt,
                                                           float* __restrict__ po0,
                                                           float* __restrict__ po1,
                                                           float* __restrict__ pm,
                                                           float* __restrict__ pl){
  __shared__ unsigned short Ks[KVB*HD];
  __shared__ unsigned short Vs[HD*KVB];
  __shared__ unsigned short Ps[8][16*PSTR];
  int tid = threadIdx.x, lane = tid & 63, w = tid >> 6;
  int l15 = lane & 15, l16 = lane >> 4;
  int b = blockIdx.x;
  int swz = (b & 7) * 96 + (b >> 3);
  int sp = swz / 384;
  int rem = swz - sp*384;
  int h = rem >> 4;
  int qt = rem & 15;
  int q0 = qt*QB + w*16;
  const unsigned short* Qh = Qn + (size_t)h*BLK*HD;
  const unsigned short* Kh = Kn + (size_t)h*SEQN*HD;
  const unsigned short* Vh = Vt + (size_t)h*HD*SEQN;
  const int kvbase = sp * (SEQN/2);
  const int NT = (SEQN/2) / KVB;

  s8v qf[4];
  #pragma unroll
  for (int kf = 0; kf < 4; kf++)
    qf[kf] = *(const s8v*)(Qh + (size_t)(q0 + l15)*HD + kf*32 + l16*8);

  fx4 o[8] = {};
  float mrow[4], lrow[4];
  #pragma unroll
  for (int j = 0; j < 4; j++){ mrow[j] = -1e30f; lrow[j] = 0.f; }

  for (int t = 0; t < NT; t++){
    int kv0 = kvbase + t*KVB;
    #pragma unroll
    for (int i = 0; i < 2; i++){
      int p = i*512 + tid;
      int row = p >> 4, cc = p & 15;
      int gc = cc ^ (row & 7);
      GL16(Kh + (size_t)(kv0+row)*HD + gc*8, Ks + p*8);
    }
    #pragma unroll
    for (int i = 0; i < 2; i++){
      int p = i*512 + tid;
      int row = p >> 3, cc = p & 7;
      int gc = cc ^ (row & 7);
      GL16(Vh + (size_t)row*SEQN + kv0 + gc*8, Vs + p*8);
    }
    __syncthreads();

    fx4 s[4] = {};
    #pragma unroll
    for (int ct = 0; ct < 4; ct++){
      #pragma unroll
      for (int kk = 0; kk < 4; kk++){
        int row = ct*16 + l15;
        int c = (kk*4 + l16) ^ (row & 7);
        s8v bb = *(const s8v*)(Ks + row*HD + c*8);
        s[ct] = MFMA(qf[kk], bb, s[ct]);
      }
    }
    float pmax[4], rssum[4];
    #pragma unroll
    for (int j = 0; j < 4; j++){
      float v = fmaxf(fmaxf(s[0][j], s[1][j]), fmaxf(s[2][j], s[3][j]));
      #pragma unroll
      for (int o2 = 1; o2 < 16; o2 <<= 1) v = fmaxf(v, __shfl_xor(v, o2));
      pmax[j] = v;
      rssum[j] = 0.f;
    }
    float need = 0.f;
    #pragma unroll
    for (int j = 0; j < 4; j++) need = fmaxf(need, pmax[j] - mrow[j]);
    if (__any(need > 8.f)){
      float alpha[4];
      #pragma unroll
      for (int j = 0; j < 4; j++){
        float mnew = fmaxf(mrow[j], pmax[j]);
        alpha[j] = __expf(mrow[j] - mnew);
        mrow[j] = mnew;
      }
      #pragma unroll
      for (int nt = 0; nt < 8; nt++)
        #pragma unroll
        for (int j = 0; j < 4; j++) o[nt][j] *= alpha[j];
      #pragma unroll
      for (int j = 0; j < 4; j++) lrow[j] *= alpha[j];
    }
    #pragma unroll
    for (int ct = 0; ct < 4; ct++)
      #pragma unroll
      for (int j = 0; j < 4; j++){
        float p = __expf(s[ct][j] - mrow[j]);
        s[ct][j] = p;
        rssum[j] += p;
      }
    #pragma unroll
    for (int j = 0; j < 4; j++){
      #pragma unroll
      for (int o2 = 1; o2 < 16; o2 <<= 1) rssum[j] += __shfl_xor(rssum[j], o2);
      lrow[j] += rssum[j];
    }

    #pragma unroll
    for (int ct = 0; ct < 4; ct++)
      #pragma unroll
      for (int j = 0; j < 4; j++){
        int row = l16*4 + j;
        int cidx = ct*16 + l15;
        Ps[w][row*PSTR + cidx] = f2bf(s[ct][j]);
      }
    asm volatile("s_waitcnt lgkmcnt(0)" ::: "memory");
    s8v pa[2];
    #pragma unroll
    for (int kk = 0; kk < 2; kk++)
      pa[kk] = *(const s8v*)(&Ps[w][l15*PSTR + (kk*4 + l16)*8]);
    #pragma unroll
    for (int nt = 0; nt < 8; nt++){
      #pragma unroll
      for (int kk = 0; kk < 2; kk++){
        int row = nt*16 + l15;
        int c = (kk*4 + l16) ^ (row & 7);
        s8v bvv = *(const s8v*)(Vs + row*KVB + c*8);
        o[nt] = MFMA(pa[kk], bvv, o[nt]);
      }
    }
    __syncthreads();
  }

  float* pop = sp ? po1 : po0;
  #pragma unroll
  for (int nt = 0; nt < 8; nt++)
    #pragma unroll
    for (int j = 0; j < 4; j++){
      int row = q0 + l16*4 + j;
      int d = nt*16 + l15;
      pop[((size_t)h*BLK + row)*HD + d] = o[nt][j];
    }
  if (l15 == 0){
    #pragma unroll
    for (int j = 0; j < 4; j++){
      int row = q0 + l16*4 + j;
      pm[(size_t)sp*HEADS*BLK + h*BLK + row] = mrow[j];
      pl[(size_t)sp*HEADS*BLK + h*BLK + row] = lrow[j];
    }
  }
}

// ---------------- merge the two split-K halves into out (+=) ----------------
__global__ __launch_bounds__(256) void flash_merge(const float* __restrict__ po0,
                                                   const float* __restrict__ po1,
                                                   const float* __restrict__ pm,
                                                   const float* __restrict__ pl,
                                                   float* __restrict__ out){
  int tid = threadIdx.x, lane = tid & 63, w = tid >> 6;
  int r = blockIdx.x*4 + w;
  int h = r >> 11, pos = r & 2047;
  float m0 = pm[r], m1 = pm[HEADS*BLK + r];
  float l0 = pl[r], l1 = pl[HEADS*BLK + r];
  float mx = fmaxf(m0, m1);
  float a0 = __expf(m0 - mx), a1 = __expf(m1 - mx);
  float li = 1.f / (l0*a0 + l1*a1);
  float s0 = a0*li, s1 = a1*li;
  size_t base = ((size_t)h*BLK + pos)*HD + 2*lane;
  float2 x0 = *(const float2*)(po0 + base);
  float2 x1 = *(const float2*)(po1 + base);
  float* op = out + (size_t)pos*DIM + h*HD + 2*lane;
  float2 cv = *(const float2*)op;
  cv.x += x0.x*s0 + x1.x*s1;
  cv.y += x0.y*s0 + x1.y*s1;
  *(float2*)op = cv;
}

extern "C" void kernel_launch(void* const* d_in, const int* in_sizes, int n_in,
                              void* d_out, int out_size, void* d_ws, size_t ws_size,
                              hipStream_t stream){
  (void)in_sizes; (void)n_in; (void)out_size;
  const float* hs       = (const float*)d_in[0];
  const float* image_emb= (const float*)d_in[1];
  const float* rope_cos = (const float*)d_in[2];
  const float* rope_sin = (const float*)d_in[3];
  const float* wq = (const float*)d_in[4];
  const float* bq = (const float*)d_in[5];
  const float* wk = (const float*)d_in[6];
  const float* bk = (const float*)d_in[7];
  const float* wv = (const float*)d_in[8];
  const float* bv = (const float*)d_in[9];
  const float* norm_q_w = (const float*)d_in[10];
  const float* norm_k_w = (const float*)d_in[11];
  const float* k_down = (const float*)d_in[14];
  const float* k_up   = (const float*)d_in[15];
  const float* v_down = (const float*)d_in[16];
  const float* v_up   = (const float*)d_in[17];
  const float* wk_ip  = (const float*)d_in[18];
  const float* wv_ip  = (const float*)d_in[19];
  float* out = (float*)d_out;

  char* ws = (char*)d_ws;
  size_t off = 0;
  auto alloc = [&](size_t bytes){ void* p = ws + off; off += (bytes + 255) & ~(size_t)255; return p; };
  unsigned short* hs_bf = (unsigned short*)alloc((size_t)SEQN*DIM*2);
  unsigned short* ie_bf = (unsigned short*)alloc((size_t)NIPN*DIM*2);
  unsigned short* w_bf[5];
  for (int i = 0; i < 5; i++) w_bf[i] = (unsigned short*)alloc((size_t)DIM*DIM*2);
  unsigned short* lw_bf[4];   // k_down, v_down, k_up, v_up
  for (int i = 0; i < 4; i++) lw_bf[i] = (unsigned short*)alloc((size_t)RANKN*DIM*2);
  unsigned short* downb = (unsigned short*)alloc((size_t)2*CONDN*RANKN*2);
  unsigned short* qb = (unsigned short*)alloc((size_t)BLK*DIM*2);
  unsigned short* kb = (unsigned short*)alloc((size_t)SEQN*DIM*2);
  unsigned short* vb = (unsigned short*)alloc((size_t)SEQN*DIM*2);
  float* ipk_pre = (float*)alloc((size_t)NIPN*DIM*4);
  float* ipv_pre = (float*)alloc((size_t)NIPN*DIM*4);
  unsigned short* ipk_bf = (unsigned short*)alloc((size_t)HEADS*NIPN*HD*2);
  unsigned short* ipv_t  = (unsigned short*)alloc((size_t)HEADS*HD*NIPN*2);
  float* po0 = (float*)alloc((size_t)HEADS*BLK*HD*4);
  float* po1 = (float*)alloc((size_t)HEADS*BLK*HD*4);
  float* pm  = (float*)alloc((size_t)2*HEADS*BLK*4);
  float* pl  = (float*)alloc((size_t)2*HEADS*BLK*4);
  if (off > ws_size) return;

  // Aliases onto dead buffers (weights consumed by gemm_256 before these are written):
  unsigned short* Qn = w_bf[0];
  unsigned short* Kn = w_bf[1];
  unsigned short* Vt = w_bf[2];

  int n4;
  n4 = SEQN*DIM/4;
  cvt_f32_bf16<<<(n4+255)/256, 256, 0, stream>>>(hs, hs_bf, n4);
  n4 = NIPN*DIM/4;
  cvt_f32_bf16<<<(n4+255)/256, 256, 0, stream>>>(image_emb, ie_bf, n4);

  // batched weight converts: 5 x DIM^2 in one dispatch, 4 x RANKN*DIM in one dispatch
  cvt_w5<<<dim3(DIM*DIM/4/256, 5), 256, 0, stream>>>(wq, wk, wv, wk_ip, wv_ip,
      w_bf[0], w_bf[1], w_bf[2], w_bf[3], w_bf[4]);
  cvt_w4<<<dim3(RANKN*DIM/4/256, 4), 256, 0, stream>>>(k_down, v_down, k_up, v_up,
      lw_bf[0], lw_bf[1], lw_bf[2], lw_bf[3]);

  lora_down_g<<<dim3(1, CONDN/128, 2), 256, 0, stream>>>(hs_bf + (size_t)BLK*DIM,
      lw_bf[0], lw_bf[1], downb);

  gemm_256<<<408, 512, 0, stream>>>(hs_bf, ie_bf,
      w_bf[0], w_bf[1], w_bf[2], w_bf[3], w_bf[4],
      bq, bk, bv, downb, lw_bf[2], lw_bf[3],
      qb, kb, vb, ipk_pre, ipv_pre);

  ipk_norm_bf<<<(NIPN*HEADS)/4, 256, 0, stream>>>(ipk_pre, ipk_bf);
  ipv_transpose<<<HEADS, 256, 0, stream>>>(ipv_pre, ipv_t);

  const float SC = 0.08838834764831845f;
  norm_rope<<<(BLK*HEADS)/4, 256, 0, stream>>>(qb, Qn, norm_q_w, rope_cos, rope_sin, BLK, SC);
  norm_rope<<<(SEQN*HEADS)/4, 256, 0, stream>>>(kb, Kn, norm_k_w, rope_cos, rope_sin, SEQN, 1.0f);
  v_transpose<<<dim3(SEQN/64, HEADS), 256, 0, stream>>>(vb, Vt);

  ip_attn_m<<<dim3(BLK/64, HEADS), 256, 0, stream>>>(qb, ipk_bf, ipv_t, out);
  flash_attn_split<<<768, 512, 0, stream>>>(Qn, Kn, Vt, po0, po1, pm, pl);
  flash_merge<<<(HEADS*BLK)/4, 256, 0, stream>>>(po0, po1, pm, pl, out);
}